// Round 1
// baseline (2329.821 us; speedup 1.0000x reference)
//
#include <hip/hip_runtime.h>
#include <hip/hip_bf16.h>
#include <cstdint>
#include <cstddef>

#define F_DIMC 256
#define FHC    1024
#define IMGH   160
#define IMGW   160
#define NTOK   25600
#define NLAY   4

using bf16 = __hip_bfloat16;
typedef __attribute__((ext_vector_type(8))) short bf16x8;
typedef __attribute__((ext_vector_type(4))) float f32x4;

// ---------------- weight convert ----------------
__global__ void cvt_bf16_k(const float* __restrict__ s, bf16* __restrict__ t, int n) {
    int i = blockIdx.x * 256 + threadIdx.x;
    if (i < n) t[i] = __float2bfloat16(s[i]);
}

// spa_dw_w (L,F,49) -> dwT (L,49,F) fp32
__global__ void dw_transpose_k(const float* __restrict__ src, float* __restrict__ dst, int n) {
    int i = blockIdx.x * 256 + threadIdx.x;
    if (i < n) {
        int f = i & (F_DIMC - 1);
        int lt = i >> 8;           // l*49 + t
        int t = lt % 49;
        int l = lt / 49;
        dst[i] = src[((size_t)l * F_DIMC + f) * 49 + t];
    }
}

// ---------------- stem: 1x1 conv (1->256) folded into depthwise 7x7 + WSiLU ----
__global__ __launch_bounds__(256)
void stem_k(const float* __restrict__ x, const float* __restrict__ w1,
            const float* __restrict__ b1, const float* __restrict__ w2,
            const float* __restrict__ b2, float* __restrict__ d)
{
    __shared__ float wt[49][F_DIMC];   // 50 KB, transposed weights
    __shared__ float xp[196];          // 14x14 patch of single-channel x
    const int tid = threadIdx.x;       // = feature f
    const int h0 = blockIdx.y * 8, w0 = blockIdx.x * 8;
    for (int idx = tid; idx < 49 * F_DIMC; idx += 256) {
        int t = idx >> 8, f = idx & 255;
        wt[t][f] = w2[f * 49 + t];
    }
    for (int p = tid; p < 196; p += 256) {
        int py = p / 14, px = p % 14;
        int gy = h0 + py - 3, gx = w0 + px - 3;
        xp[p] = ((unsigned)gy < IMGH && (unsigned)gx < IMGW) ? x[gy * IMGW + gx] : 0.f;
    }
    __syncthreads();
    const float w1f = w1[tid], b1f = b1[tid], b2f = b2[tid];
    for (int pi = 0; pi < 64; ++pi) {
        int py = pi >> 3, px = pi & 7;
        float sx = 0.f, sw = 0.f;
        for (int t = 0; t < 49; ++t) {
            int ky = t / 7, kx = t % 7;
            int gy = h0 + py + ky - 3, gx = w0 + px + kx - 3;
            float wv = wt[t][tid];
            if ((unsigned)gy < IMGH && (unsigned)gx < IMGW) {
                sx += xp[(py + ky) * 14 + (px + kx)] * wv;
                sw += wv;     // pad is applied AFTER the 1x1 conv, so b1 only sums valid taps
            }
        }
        float u = w1f * sx + b1f * sw + b2f;
        d[(size_t)((h0 + py) * IMGW + (w0 + px)) * F_DIMC + tid] = u / (1.f + __expf(-4.f * u));
    }
}

// ---------------- wave-level LayerNorm over F=256 (64 lanes x 4) -------------
__device__ __forceinline__ void wave_ln(float* x, const float* __restrict__ w,
                                        const float* __restrict__ b, int lane)
{
    float s = x[0] + x[1] + x[2] + x[3];
    #pragma unroll
    for (int m = 1; m < 64; m <<= 1) s += __shfl_xor(s, m, 64);
    float mu = s * 0.00390625f;
    float t0 = x[0] - mu, t1 = x[1] - mu, t2 = x[2] - mu, t3 = x[3] - mu;
    float v = t0 * t0 + t1 * t1 + t2 * t2 + t3 * t3;
    #pragma unroll
    for (int m = 1; m < 64; m <<= 1) v += __shfl_xor(v, m, 64);
    float inv = rsqrtf(v * 0.00390625f + 1e-5f);
    f32x4 wv = *(const f32x4*)(w + lane * 4);
    f32x4 bv = *(const f32x4*)(b + lane * 4);
    x[0] = t0 * inv * wv[0] + bv[0];
    x[1] = t1 * inv * wv[1] + bv[1];
    x[2] = t2 * inv * wv[2] + bv[2];
    x[3] = t3 * inv * wv[3] + bv[3];
}

union Pack4 { bf16 h[4]; uint2 u; };

// ---------------- LN (+optional LN0) + SA token mix -> xk,xv,xr (bf16) -------
template<bool LN0>
__global__ __launch_bounds__(256)
void lnmix_sa_k(float* __restrict__ d, const float* __restrict__ sp,
                const float* __restrict__ ln0w, const float* __restrict__ ln0b,
                const float* __restrict__ lnw, const float* __restrict__ lnb,
                const float* __restrict__ tmk, const float* __restrict__ tmv,
                const float* __restrict__ tmr,
                bf16* __restrict__ xk, bf16* __restrict__ xv, bf16* __restrict__ xr)
{
    const int lane = threadIdx.x & 63;
    const int n = blockIdx.x * 4 + (threadIdx.x >> 6);
    const int base = n * F_DIMC + lane * 4;
    f32x4 dv = *(const f32x4*)(d + base);
    float xo[4] = {dv[0], dv[1], dv[2], dv[3]};
    if (LN0) {
        wave_ln(xo, ln0w, ln0b, lane);
        f32x4 o = {xo[0], xo[1], xo[2], xo[3]};
        *(f32x4*)(d + base) = o;
    }
    float xs[4] = {xo[0], xo[1], xo[2], xo[3]};
    wave_ln(xs, lnw, lnb, lane);
    f32x4 spv = *(const f32x4*)(sp + base);
    f32x4 k4 = *(const f32x4*)(tmk + lane * 4);
    f32x4 v4 = *(const f32x4*)(tmv + lane * 4);
    f32x4 r4 = *(const f32x4*)(tmr + lane * 4);
    Pack4 pk, pv, pr;
    #pragma unroll
    for (int j = 0; j < 4; ++j) {
        pk.h[j] = __float2bfloat16(xs[j] * k4[j] + spv[j] * (1.f - k4[j]));
        pv.h[j] = __float2bfloat16(xs[j] * v4[j] + spv[j] * (1.f - v4[j]));
        pr.h[j] = __float2bfloat16(xs[j] * r4[j] + spv[j] * (1.f - r4[j]));
    }
    *(uint2*)(xk + base) = pk.u;
    *(uint2*)(xv + base) = pv.u;
    *(uint2*)(xr + base) = pr.u;
}

// ---------------- LN + FFN token mix -> xk,xr (bf16) -------------------------
__global__ __launch_bounds__(256)
void lnmix_ff_k(const float* __restrict__ d, const float* __restrict__ sp,
                const float* __restrict__ lnw, const float* __restrict__ lnb,
                const float* __restrict__ tmk, const float* __restrict__ tmr,
                bf16* __restrict__ xk, bf16* __restrict__ xr)
{
    const int lane = threadIdx.x & 63;
    const int n = blockIdx.x * 4 + (threadIdx.x >> 6);
    const int base = n * F_DIMC + lane * 4;
    f32x4 dv = *(const f32x4*)(d + base);
    float xs[4] = {dv[0], dv[1], dv[2], dv[3]};
    wave_ln(xs, lnw, lnb, lane);
    f32x4 spv = *(const f32x4*)(sp + base);
    f32x4 k4 = *(const f32x4*)(tmk + lane * 4);
    f32x4 r4 = *(const f32x4*)(tmr + lane * 4);
    Pack4 pk, pr;
    #pragma unroll
    for (int j = 0; j < 4; ++j) {
        pk.h[j] = __float2bfloat16(xs[j] * k4[j] + spv[j] * (1.f - k4[j]));
        pr.h[j] = __float2bfloat16(xs[j] * r4[j] + spv[j] * (1.f - r4[j]));
    }
    *(uint2*)(xk + base) = pk.u;
    *(uint2*)(xr + base) = pr.u;
}

// ---------------- WKV single step + r*wkv -> bf16 ----------------------------
__global__ __launch_bounds__(256)
void wkv_k(const float* __restrict__ r_, const float* __restrict__ k_,
           const float* __restrict__ v_, const float* __restrict__ aa,
           const float* __restrict__ bb, const float* __restrict__ pp,
           const float* __restrict__ tf, bf16* __restrict__ out)
{
    int i = blockIdx.x * 256 + threadIdx.x;   // float4 group index, NF/4 total
    int f0 = (i << 2) & (F_DIMC - 1);
    f32x4 r4 = *(const f32x4*)(r_ + (size_t)i * 4);
    f32x4 k4 = *(const f32x4*)(k_ + (size_t)i * 4);
    f32x4 v4 = *(const f32x4*)(v_ + (size_t)i * 4);
    f32x4 a4 = *(const f32x4*)(aa + (size_t)i * 4);
    f32x4 b4 = *(const f32x4*)(bb + (size_t)i * 4);
    f32x4 p4 = *(const f32x4*)(pp + (size_t)i * 4);
    f32x4 t4 = *(const f32x4*)(tf + f0);
    Pack4 po;
    #pragma unroll
    for (int j = 0; j < 4; ++j) {
        float ww = t4[j] + k4[j];
        float p = fmaxf(p4[j], ww);
        float e1 = __expf(p4[j] - p);
        float e2 = __expf(ww - p);
        float wkv = (e1 * a4[j] + e2 * v4[j]) / (e1 * b4[j] + e2);
        po.h[j] = __float2bfloat16(r4[j] * wkv);
    }
    *(uint2*)(out + (size_t)i * 4) = po.u;
}

// ---------------- depthwise 7x7 conv on NHWC d, bf16 out ---------------------
__global__ __launch_bounds__(256)
void dwconv_k(const float* __restrict__ d, const float* __restrict__ wT,
              const float* __restrict__ bias, bf16* __restrict__ out)
{
    __shared__ float patch[100 * 64];   // 10x10 pixels x 64 features
    __shared__ float wt[49 * 64];
    const int lane = threadIdx.x;       // 0..63 (feature)
    const int ty = threadIdx.y;         // 0..3
    const int f0 = blockIdx.z * 64;
    const int w0 = blockIdx.x * 4, h0 = blockIdx.y * 4;
    for (int t = ty; t < 49; t += 4) wt[t * 64 + lane] = wT[t * F_DIMC + f0 + lane];
    for (int p = ty; p < 100; p += 4) {
        int py = p / 10, px = p % 10;
        int gy = h0 + py - 3, gx = w0 + px - 3;
        float v = 0.f;
        if ((unsigned)gy < IMGH && (unsigned)gx < IMGW)
            v = d[(size_t)(gy * IMGW + gx) * F_DIMC + f0 + lane];
        patch[p * 64 + lane] = v;
    }
    __syncthreads();
    const float b = bias[f0 + lane];
    for (int pi = ty; pi < 16; pi += 4) {
        int py = pi >> 2, px = pi & 3;
        float acc = b;
        #pragma unroll
        for (int t = 0; t < 49; ++t) {
            int ky = t / 7, kx = t % 7;
            acc += patch[((py + ky) * 10 + (px + kx)) * 64 + lane] * wt[t * 64 + lane];
        }
        out[(size_t)((h0 + py) * IMGW + (w0 + px)) * F_DIMC + f0 + lane] = __float2bfloat16(acc);
    }
}

// ---------------- MFMA GEMM: C(MxN) = A(MxK) * W(NxK)^T, fused epilogues -----
// EPI: 0 = store f32, 1 = sigmoid->f32, 2 = relu^2 -> bf16,
//      3 = Cf += out, 4 = Cf += aux*out, 5 = Cf += out + bias[col]
#define GEMM_BK 64
template<int EPI>
__global__ __launch_bounds__(256)
void gemm_bt(const bf16* __restrict__ A, const bf16* __restrict__ Bw,
             int K, int Nout,
             float* __restrict__ Cf, bf16* __restrict__ Cb,
             const float* __restrict__ aux, const float* __restrict__ bias)
{
    __shared__ __align__(16) bf16 As[128 * GEMM_BK];
    __shared__ __align__(16) bf16 Bs[128 * GEMM_BK];
    const int tid = threadIdx.x;
    const int m0 = blockIdx.x * 128;
    const int n0 = blockIdx.y * 128;
    const int lane = tid & 63;
    const int wave = tid >> 6;
    const int wr = wave >> 1, wc = wave & 1;   // 2x2 waves, 64x64 each
    f32x4 acc[4][4];
    #pragma unroll
    for (int m = 0; m < 4; ++m)
        #pragma unroll
        for (int n = 0; n < 4; ++n) acc[m][n] = (f32x4){0.f, 0.f, 0.f, 0.f};

    for (int k0 = 0; k0 < K; k0 += GEMM_BK) {
        #pragma unroll
        for (int s = 0; s < 4; ++s) {
            int e = s * 2048 + tid * 8;
            int row = e >> 6, col = e & 63;
            __builtin_amdgcn_global_load_lds(
                (const __attribute__((address_space(1))) void*)(A + (size_t)(m0 + row) * K + (k0 + col)),
                (__attribute__((address_space(3))) void*)(&As[e]), 16, 0, 0);
        }
        #pragma unroll
        for (int s = 0; s < 4; ++s) {
            int e = s * 2048 + tid * 8;
            int row = e >> 6, col = e & 63;
            __builtin_amdgcn_global_load_lds(
                (const __attribute__((address_space(1))) void*)(Bw + (size_t)(n0 + row) * K + (k0 + col)),
                (__attribute__((address_space(3))) void*)(&Bs[e]), 16, 0, 0);
        }
        __syncthreads();   // drains vmcnt (compiler emits s_waitcnt vmcnt(0) before s_barrier)
        #pragma unroll
        for (int kk = 0; kk < GEMM_BK; kk += 32) {
            const int lr = lane & 15;
            const int lk = kk + (lane >> 4) * 8;
            bf16x8 af[4], bfr[4];
            #pragma unroll
            for (int m = 0; m < 4; ++m)
                af[m] = *(const bf16x8*)&As[(wr * 64 + m * 16 + lr) * GEMM_BK + lk];
            #pragma unroll
            for (int n = 0; n < 4; ++n)
                bfr[n] = *(const bf16x8*)&Bs[(wc * 64 + n * 16 + lr) * GEMM_BK + lk];
            #pragma unroll
            for (int m = 0; m < 4; ++m)
                #pragma unroll
                for (int n = 0; n < 4; ++n)
                    acc[m][n] = __builtin_amdgcn_mfma_f32_16x16x32_bf16(af[m], bfr[n], acc[m][n], 0, 0, 0);
        }
        __syncthreads();
    }
    const int lr0 = (lane >> 4) * 4;
    const int lc = lane & 15;
    #pragma unroll
    for (int m = 0; m < 4; ++m) {
        #pragma unroll
        for (int n = 0; n < 4; ++n) {
            #pragma unroll
            for (int j = 0; j < 4; ++j) {
                int row = m0 + wr * 64 + m * 16 + lr0 + j;
                int col = n0 + wc * 64 + n * 16 + lc;
                size_t cidx = (size_t)row * Nout + col;
                float v = acc[m][n][j];
                if constexpr (EPI == 0) Cf[cidx] = v;
                else if constexpr (EPI == 1) Cf[cidx] = 1.f / (1.f + __expf(-v));
                else if constexpr (EPI == 2) { float t = fmaxf(v, 0.f); Cb[cidx] = __float2bfloat16(t * t); }
                else if constexpr (EPI == 3) Cf[cidx] += v;
                else if constexpr (EPI == 4) Cf[cidx] += aux[cidx] * v;
                else if constexpr (EPI == 5) Cf[cidx] += v + bias[col];
            }
        }
    }
}

// ---------------- final (N,F) -> (F,H,W) transpose ---------------------------
__global__ __launch_bounds__(256)
void transpose_out_k(const float* __restrict__ d, float* __restrict__ out)
{
    __shared__ float tile[32][33];
    const int n0 = blockIdx.x * 32, f0 = blockIdx.y * 32;
    const int tx = threadIdx.x, ty = threadIdx.y;
    for (int r = ty; r < 32; r += 8) tile[r][tx] = d[(size_t)(n0 + r) * F_DIMC + f0 + tx];
    __syncthreads();
    for (int r = ty; r < 32; r += 8) out[(size_t)(f0 + r) * NTOK + n0 + tx] = tile[tx][r];
}

// =============================================================================
extern "C" void kernel_launch(void* const* d_in, const int* in_sizes, int n_in,
                              void* d_out, int out_size, void* d_ws, size_t ws_size,
                              hipStream_t stream)
{
    if (n_in < 30) return;
    const float* x        = (const float*)d_in[0];
    const float* cin_w1   = (const float*)d_in[1];
    const float* cin_b1   = (const float*)d_in[2];
    const float* cin_w2   = (const float*)d_in[3];
    const float* cin_b2   = (const float*)d_in[4];
    const float* ln0_w    = (const float*)d_in[5];
    const float* ln0_b    = (const float*)d_in[6];
    const float* ln1_w    = (const float*)d_in[7];
    const float* ln1_b    = (const float*)d_in[8];
    const float* ln2_w    = (const float*)d_in[9];
    const float* ln2_b    = (const float*)d_in[10];
    const float* att_tmk  = (const float*)d_in[11];
    const float* att_tmv  = (const float*)d_in[12];
    const float* att_tmr  = (const float*)d_in[13];
    const float* ffn_tmk  = (const float*)d_in[14];
    const float* ffn_tmr  = (const float*)d_in[15];
    const float* att_tf   = (const float*)d_in[16];
    /* d_in[17] = att_td, unused by the reference's single step */
    const float* att_kw   = (const float*)d_in[18];
    const float* att_vw   = (const float*)d_in[19];
    const float* att_rw   = (const float*)d_in[20];
    const float* att_ow   = (const float*)d_in[21];
    const float* ffn_rw   = (const float*)d_in[22];
    const float* ffn_kw   = (const float*)d_in[23];
    const float* ffn_vw   = (const float*)d_in[24];
    const float* spa_dw_w = (const float*)d_in[25];
    const float* spa_dw_b = (const float*)d_in[26];
    const float* spa_pw_w = (const float*)d_in[27];
    const float* spa_pw_b = (const float*)d_in[28];
    const float* state0   = (const float*)d_in[29];
    float* out = (float*)d_out;

    const size_t NF = (size_t)NTOK * F_DIMC;
    char* wsp = (char*)d_ws;
    size_t off = 0;
    auto alloc = [&](size_t bytes) -> void* {
        void* p = wsp + off;
        off += (bytes + 255) & ~(size_t)255;
        return p;
    };
    float* d_buf = (float*)alloc(NF * 4);
    float* Gk    = (float*)alloc(NF * 4);
    float* Gv    = (float*)alloc(NF * 4);
    float* Gr    = (float*)alloc(NF * 4);
    bf16*  xk    = (bf16*)alloc(NF * 2);
    bf16*  xv    = (bf16*)alloc(NF * 2);
    bf16*  xr    = (bf16*)alloc(NF * 2);
    bf16*  ab    = (bf16*)alloc(NF * 2);              // rwkv / dwconv-out (reused)
    bf16*  kkb   = (bf16*)alloc((size_t)NTOK * FHC * 2);
    const size_t WSQ = (size_t)NLAY * F_DIMC * F_DIMC;
    bf16* kwb  = (bf16*)alloc(WSQ * 2);
    bf16* vwb  = (bf16*)alloc(WSQ * 2);
    bf16* rwb  = (bf16*)alloc(WSQ * 2);
    bf16* owb  = (bf16*)alloc(WSQ * 2);
    bf16* frwb = (bf16*)alloc(WSQ * 2);
    bf16* fkwb = (bf16*)alloc((size_t)NLAY * FHC * F_DIMC * 2);
    bf16* fvwb = (bf16*)alloc((size_t)NLAY * F_DIMC * FHC * 2);
    bf16* pwb  = (bf16*)alloc(WSQ * 2);
    float* dwT = (float*)alloc((size_t)NLAY * 49 * F_DIMC * 4);
    if (off > ws_size) return;   // workspace too small -> clean zero-output failure

    auto cvt = [&](const float* s, bf16* t, int n) {
        cvt_bf16_k<<<dim3((n + 255) / 256), dim3(256), 0, stream>>>(s, t, n);
    };
    cvt(att_kw, kwb, (int)WSQ);
    cvt(att_vw, vwb, (int)WSQ);
    cvt(att_rw, rwb, (int)WSQ);
    cvt(att_ow, owb, (int)WSQ);
    cvt(ffn_rw, frwb, (int)WSQ);
    cvt(ffn_kw, fkwb, NLAY * FHC * F_DIMC);
    cvt(ffn_vw, fvwb, NLAY * F_DIMC * FHC);
    cvt(spa_pw_w, pwb, (int)WSQ);
    {
        int n = NLAY * 49 * F_DIMC;
        dw_transpose_k<<<dim3((n + 255) / 256), dim3(256), 0, stream>>>(spa_dw_w, dwT, n);
    }

    stem_k<<<dim3(IMGW / 8, IMGH / 8), dim3(256), 0, stream>>>(x, cin_w1, cin_b1, cin_w2, cin_b2, d_buf);

    for (int i = 0; i < NLAY; ++i) {
        const float* sp_ff = state0 + (size_t)(5 * i + 0) * NF;
        const float* sp_at = state0 + (size_t)(5 * i + 1) * NF;
        const float* aa    = state0 + (size_t)(5 * i + 2) * NF;
        const float* bb    = state0 + (size_t)(5 * i + 3) * NF;
        const float* pp    = state0 + (size_t)(5 * i + 4) * NF;
        const float* l1w = ln1_w + i * F_DIMC, *l1b = ln1_b + i * F_DIMC;
        const float* l2w = ln2_w + i * F_DIMC, *l2b = ln2_b + i * F_DIMC;
        const float* tmk = att_tmk + i * F_DIMC, *tmv = att_tmv + i * F_DIMC, *tmr = att_tmr + i * F_DIMC;
        const float* ftmk = ffn_tmk + i * F_DIMC, *ftmr = ffn_tmr + i * F_DIMC;
        const float* tf = att_tf + i * F_DIMC;
        const bf16* kw_i  = kwb  + (size_t)i * F_DIMC * F_DIMC;
        const bf16* vw_i  = vwb  + (size_t)i * F_DIMC * F_DIMC;
        const bf16* rw_i  = rwb  + (size_t)i * F_DIMC * F_DIMC;
        const bf16* ow_i  = owb  + (size_t)i * F_DIMC * F_DIMC;
        const bf16* frw_i = frwb + (size_t)i * F_DIMC * F_DIMC;
        const bf16* fkw_i = fkwb + (size_t)i * FHC * F_DIMC;
        const bf16* fvw_i = fvwb + (size_t)i * F_DIMC * FHC;
        const bf16* pw_i  = pwb  + (size_t)i * F_DIMC * F_DIMC;
        const float* dwT_i = dwT + (size_t)i * 49 * F_DIMC;
        const float* dwb_i = spa_dw_b + i * F_DIMC;
        const float* pwbias_i = spa_pw_b + i * F_DIMC;

        if (i == 0)
            lnmix_sa_k<true><<<dim3(NTOK / 4), dim3(256), 0, stream>>>(
                d_buf, sp_at, ln0_w, ln0_b, l1w, l1b, tmk, tmv, tmr, xk, xv, xr);
        else
            lnmix_sa_k<false><<<dim3(NTOK / 4), dim3(256), 0, stream>>>(
                d_buf, sp_at, ln0_w, ln0_b, l1w, l1b, tmk, tmv, tmr, xk, xv, xr);

        gemm_bt<0><<<dim3(NTOK / 128, 2), dim3(256), 0, stream>>>(xk, kw_i, F_DIMC, F_DIMC, Gk, nullptr, nullptr, nullptr);
        gemm_bt<0><<<dim3(NTOK / 128, 2), dim3(256), 0, stream>>>(xv, vw_i, F_DIMC, F_DIMC, Gv, nullptr, nullptr, nullptr);
        gemm_bt<1><<<dim3(NTOK / 128, 2), dim3(256), 0, stream>>>(xr, rw_i, F_DIMC, F_DIMC, Gr, nullptr, nullptr, nullptr);
        wkv_k<<<dim3((int)(NF / 4 / 256)), dim3(256), 0, stream>>>(Gr, Gk, Gv, aa, bb, pp, tf, ab);
        gemm_bt<3><<<dim3(NTOK / 128, 2), dim3(256), 0, stream>>>(ab, ow_i, F_DIMC, F_DIMC, d_buf, nullptr, nullptr, nullptr);

        lnmix_ff_k<<<dim3(NTOK / 4), dim3(256), 0, stream>>>(d_buf, sp_ff, l2w, l2b, ftmk, ftmr, xk, xr);
        gemm_bt<1><<<dim3(NTOK / 128, 2), dim3(256), 0, stream>>>(xr, frw_i, F_DIMC, F_DIMC, Gr, nullptr, nullptr, nullptr);
        gemm_bt<2><<<dim3(NTOK / 128, 8), dim3(256), 0, stream>>>(xk, fkw_i, F_DIMC, FHC, nullptr, kkb, nullptr, nullptr);
        gemm_bt<4><<<dim3(NTOK / 128, 2), dim3(256), 0, stream>>>(kkb, fvw_i, FHC, F_DIMC, d_buf, nullptr, Gr, nullptr);

        dwconv_k<<<dim3(IMGW / 4, IMGH / 4, 4), dim3(64, 4), 0, stream>>>(d_buf, dwT_i, dwb_i, ab);
        gemm_bt<5><<<dim3(NTOK / 128, 2), dim3(256), 0, stream>>>(ab, pw_i, F_DIMC, F_DIMC, d_buf, nullptr, nullptr, pwbias_i);
    }

    transpose_out_k<<<dim3(NTOK / 32, F_DIMC / 32), dim3(32, 8), 0, stream>>>(d_buf, out);
}

// Round 2
// 1943.467 us; speedup vs baseline: 1.1988x; 1.1988x over previous
//
#include <hip/hip_runtime.h>
#include <hip/hip_bf16.h>
#include <cstdint>
#include <cstddef>

#define F_DIMC 256
#define FHC    1024
#define IMGH   160
#define IMGW   160
#define NTOK   25600
#define NLAY   4

using bf16 = __hip_bfloat16;
typedef __attribute__((ext_vector_type(8))) short bf16x8;
typedef __attribute__((ext_vector_type(4))) float f32x4;

// ---------------- weight converts (merged) ----------------
struct Cvt6 { const float* s[6]; bf16* d[6]; };
__global__ void cvt6_k(Cvt6 a, int n) {
    int z = blockIdx.y;
    int i = blockIdx.x * 256 + threadIdx.x;
    if (i < n) a.d[z][i] = __float2bfloat16(a.s[z][i]);
}
struct Cvt2 { const float* s[2]; bf16* d[2]; };
__global__ void cvt2_k(Cvt2 a, int n) {
    int z = blockIdx.y;
    int i = blockIdx.x * 256 + threadIdx.x;
    if (i < n) a.d[z][i] = __float2bfloat16(a.s[z][i]);
}

// spa_dw_w (L,F,49) -> dwT (L,49,F) fp32
__global__ void dw_transpose_k(const float* __restrict__ src, float* __restrict__ dst, int n) {
    int i = blockIdx.x * 256 + threadIdx.x;
    if (i < n) {
        int f = i & (F_DIMC - 1);
        int lt = i >> 8;           // l*49 + t
        int t = lt % 49;
        int l = lt / 49;
        dst[i] = src[((size_t)l * F_DIMC + f) * 49 + t];
    }
}

// ---------------- stem v2: branchless, strip-parallel ------------------------
// block: 256 thr = 64 features x 4 pixel-subthreads; strip = 16 px along x.
// grid: (160 rows * 10 strips, 4 feature groups)
__global__ __launch_bounds__(256)
void stem2_k(const float* __restrict__ x, const float* __restrict__ w1,
             const float* __restrict__ b1, const float* __restrict__ w2,
             const float* __restrict__ b2, float* __restrict__ d)
{
    __shared__ float wts[49][64];
    __shared__ float w1s[64], b1s[64], b2s[64];
    __shared__ float2 xp[7][22];        // (value, valid) padded strip
    const int tid = threadIdx.x;
    const int f0 = blockIdx.y * 64;
    const int y = blockIdx.x / 10;
    const int x0 = (blockIdx.x % 10) * 16;

    for (int idx = tid; idx < 49 * 64; idx += 256) {
        int t = idx >> 6, fl = idx & 63;
        wts[t][fl] = w2[(f0 + fl) * 49 + t];
    }
    if (tid < 64) {
        w1s[tid] = w1[f0 + tid];
        b1s[tid] = b1[f0 + tid];
        b2s[tid] = b2[f0 + tid];
    }
    for (int p = tid; p < 7 * 22; p += 256) {
        int py = p / 22, px = p % 22;
        int gy = y + py - 3, gx = x0 + px - 3;
        bool ok = (unsigned)gy < IMGH && (unsigned)gx < IMGW;
        xp[py][px] = ok ? make_float2(x[gy * IMGW + gx], 1.f) : make_float2(0.f, 0.f);
    }
    __syncthreads();

    const int fl = tid & 63;
    const int xbase = (tid >> 6) * 4;
    float acc[4] = {0.f, 0.f, 0.f, 0.f}, accw[4] = {0.f, 0.f, 0.f, 0.f};
    #pragma unroll
    for (int ky = 0; ky < 7; ++ky) {
        float2 row[10];
        #pragma unroll
        for (int q = 0; q < 10; ++q) row[q] = xp[ky][xbase + q];
        #pragma unroll
        for (int kx = 0; kx < 7; ++kx) {
            float w = wts[ky * 7 + kx][fl];
            #pragma unroll
            for (int j = 0; j < 4; ++j) {
                acc[j]  = fmaf(row[j + kx].x, w, acc[j]);
                accw[j] = fmaf(row[j + kx].y, w, accw[j]);
            }
        }
    }
    const float w1f = w1s[fl], b1f = b1s[fl], b2f = b2s[fl];
    #pragma unroll
    for (int j = 0; j < 4; ++j) {
        float u = fmaf(w1f, acc[j], fmaf(b1f, accw[j], b2f));
        int pix = y * IMGW + x0 + xbase + j;
        d[(size_t)pix * F_DIMC + f0 + fl] = u / (1.f + __expf(-4.f * u));
    }
}

// ---------------- wave-level LayerNorm over F=256 (64 lanes x 4) -------------
__device__ __forceinline__ void wave_ln(float* x, const float* __restrict__ w,
                                        const float* __restrict__ b, int lane)
{
    float s = x[0] + x[1] + x[2] + x[3];
    #pragma unroll
    for (int m = 1; m < 64; m <<= 1) s += __shfl_xor(s, m, 64);
    float mu = s * 0.00390625f;
    float t0 = x[0] - mu, t1 = x[1] - mu, t2 = x[2] - mu, t3 = x[3] - mu;
    float v = t0 * t0 + t1 * t1 + t2 * t2 + t3 * t3;
    #pragma unroll
    for (int m = 1; m < 64; m <<= 1) v += __shfl_xor(v, m, 64);
    float inv = rsqrtf(v * 0.00390625f + 1e-5f);
    f32x4 wv = *(const f32x4*)(w + lane * 4);
    f32x4 bv = *(const f32x4*)(b + lane * 4);
    x[0] = t0 * inv * wv[0] + bv[0];
    x[1] = t1 * inv * wv[1] + bv[1];
    x[2] = t2 * inv * wv[2] + bv[2];
    x[3] = t3 * inv * wv[3] + bv[3];
}

union Pack4 { bf16 h[4]; uint2 u; };

// ---------------- LN (+optional LN0) + SA token mix -> xk,xv,xr (bf16) -------
template<bool LN0>
__global__ __launch_bounds__(256)
void lnmix_sa_k(float* __restrict__ d, const float* __restrict__ sp,
                const float* __restrict__ ln0w, const float* __restrict__ ln0b,
                const float* __restrict__ lnw, const float* __restrict__ lnb,
                const float* __restrict__ tmk, const float* __restrict__ tmv,
                const float* __restrict__ tmr,
                bf16* __restrict__ xk, bf16* __restrict__ xv, bf16* __restrict__ xr)
{
    const int lane = threadIdx.x & 63;
    const int n = blockIdx.x * 4 + (threadIdx.x >> 6);
    const int base = n * F_DIMC + lane * 4;
    f32x4 dv = *(const f32x4*)(d + base);
    float xo[4] = {dv[0], dv[1], dv[2], dv[3]};
    if (LN0) {
        wave_ln(xo, ln0w, ln0b, lane);
        f32x4 o = {xo[0], xo[1], xo[2], xo[3]};
        *(f32x4*)(d + base) = o;
    }
    float xs[4] = {xo[0], xo[1], xo[2], xo[3]};
    wave_ln(xs, lnw, lnb, lane);
    f32x4 spv = *(const f32x4*)(sp + base);
    f32x4 k4 = *(const f32x4*)(tmk + lane * 4);
    f32x4 v4 = *(const f32x4*)(tmv + lane * 4);
    f32x4 r4 = *(const f32x4*)(tmr + lane * 4);
    Pack4 pk, pv, pr;
    #pragma unroll
    for (int j = 0; j < 4; ++j) {
        pk.h[j] = __float2bfloat16(xs[j] * k4[j] + spv[j] * (1.f - k4[j]));
        pv.h[j] = __float2bfloat16(xs[j] * v4[j] + spv[j] * (1.f - v4[j]));
        pr.h[j] = __float2bfloat16(xs[j] * r4[j] + spv[j] * (1.f - r4[j]));
    }
    *(uint2*)(xk + base) = pk.u;
    *(uint2*)(xv + base) = pv.u;
    *(uint2*)(xr + base) = pr.u;
}

// ---------------- LN + FFN token mix -> xk,xr (bf16) -------------------------
__global__ __launch_bounds__(256)
void lnmix_ff_k(const float* __restrict__ d, const float* __restrict__ sp,
                const float* __restrict__ lnw, const float* __restrict__ lnb,
                const float* __restrict__ tmk, const float* __restrict__ tmr,
                bf16* __restrict__ xk, bf16* __restrict__ xr)
{
    const int lane = threadIdx.x & 63;
    const int n = blockIdx.x * 4 + (threadIdx.x >> 6);
    const int base = n * F_DIMC + lane * 4;
    f32x4 dv = *(const f32x4*)(d + base);
    float xs[4] = {dv[0], dv[1], dv[2], dv[3]};
    wave_ln(xs, lnw, lnb, lane);
    f32x4 spv = *(const f32x4*)(sp + base);
    f32x4 k4 = *(const f32x4*)(tmk + lane * 4);
    f32x4 r4 = *(const f32x4*)(tmr + lane * 4);
    Pack4 pk, pr;
    #pragma unroll
    for (int j = 0; j < 4; ++j) {
        pk.h[j] = __float2bfloat16(xs[j] * k4[j] + spv[j] * (1.f - k4[j]));
        pr.h[j] = __float2bfloat16(xs[j] * r4[j] + spv[j] * (1.f - r4[j]));
    }
    *(uint2*)(xk + base) = pk.u;
    *(uint2*)(xr + base) = pr.u;
}

// ---------------- WKV single step + r*wkv -> bf16 ----------------------------
__global__ __launch_bounds__(256)
void wkv_k(const float* __restrict__ r_, const float* __restrict__ k_,
           const float* __restrict__ v_, const float* __restrict__ aa,
           const float* __restrict__ bb, const float* __restrict__ pp,
           const float* __restrict__ tf, bf16* __restrict__ out)
{
    int i = blockIdx.x * 256 + threadIdx.x;   // float4 group index, NF/4 total
    int f0 = (i << 2) & (F_DIMC - 1);
    f32x4 r4 = *(const f32x4*)(r_ + (size_t)i * 4);
    f32x4 k4 = *(const f32x4*)(k_ + (size_t)i * 4);
    f32x4 v4 = *(const f32x4*)(v_ + (size_t)i * 4);
    f32x4 a4 = *(const f32x4*)(aa + (size_t)i * 4);
    f32x4 b4 = *(const f32x4*)(bb + (size_t)i * 4);
    f32x4 p4 = *(const f32x4*)(pp + (size_t)i * 4);
    f32x4 t4 = *(const f32x4*)(tf + f0);
    Pack4 po;
    #pragma unroll
    for (int j = 0; j < 4; ++j) {
        float ww = t4[j] + k4[j];
        float p = fmaxf(p4[j], ww);
        float e1 = __expf(p4[j] - p);
        float e2 = __expf(ww - p);
        float wkv = (e1 * a4[j] + e2 * v4[j]) / (e1 * b4[j] + e2);
        po.h[j] = __float2bfloat16(r4[j] * wkv);
    }
    *(uint2*)(out + (size_t)i * 4) = po.u;
}

// ---------------- depthwise 7x7 conv on NHWC d, bf16 out ---------------------
__global__ __launch_bounds__(256)
void dwconv_k(const float* __restrict__ d, const float* __restrict__ wT,
              const float* __restrict__ bias, bf16* __restrict__ out)
{
    __shared__ float patch[100 * 64];   // 10x10 pixels x 64 features
    __shared__ float wt[49 * 64];
    const int lane = threadIdx.x;       // 0..63 (feature)
    const int ty = threadIdx.y;         // 0..3
    const int f0 = blockIdx.z * 64;
    const int w0 = blockIdx.x * 4, h0 = blockIdx.y * 4;
    for (int t = ty; t < 49; t += 4) wt[t * 64 + lane] = wT[t * F_DIMC + f0 + lane];
    for (int p = ty; p < 100; p += 4) {
        int py = p / 10, px = p % 10;
        int gy = h0 + py - 3, gx = w0 + px - 3;
        float v = 0.f;
        if ((unsigned)gy < IMGH && (unsigned)gx < IMGW)
            v = d[(size_t)(gy * IMGW + gx) * F_DIMC + f0 + lane];
        patch[p * 64 + lane] = v;
    }
    __syncthreads();
    const float b = bias[f0 + lane];
    for (int pi = ty; pi < 16; pi += 4) {
        int py = pi >> 2, px = pi & 3;
        float acc = b;
        #pragma unroll
        for (int t = 0; t < 49; ++t) {
            int ky = t / 7, kx = t % 7;
            acc += patch[((py + ky) * 10 + (px + kx)) * 64 + lane] * wt[t * 64 + lane];
        }
        out[(size_t)((h0 + py) * IMGW + (w0 + px)) * F_DIMC + f0 + lane] = __float2bfloat16(acc);
    }
}

// ---------------- MFMA GEMM core (128x128 tile, BK=64) -----------------------
#define GEMM_BK 64

// batched SA GEMM: z=0: xk@kw->Gk, z=1: xv@vw->Gv, z=2: xr@rw->sigmoid->Gr
struct G3 { const bf16* A0; const bf16* A1; const bf16* A2;
            const bf16* W0; const bf16* W1; const bf16* W2;
            float* C0; float* C1; float* C2; };
__global__ __launch_bounds__(256)
void gemm3_k(G3 g)
{
    __shared__ __align__(16) bf16 As[128 * GEMM_BK];
    __shared__ __align__(16) bf16 Bs[128 * GEMM_BK];
    const int z = blockIdx.z;
    const bf16* __restrict__ A  = z == 0 ? g.A0 : z == 1 ? g.A1 : g.A2;
    const bf16* __restrict__ Bw = z == 0 ? g.W0 : z == 1 ? g.W1 : g.W2;
    float* __restrict__ C       = z == 0 ? g.C0 : z == 1 ? g.C1 : g.C2;
    const int tid = threadIdx.x;
    const int m0 = blockIdx.x * 128;
    const int n0 = blockIdx.y * 128;
    const int lane = tid & 63;
    const int wave = tid >> 6;
    const int wr = wave >> 1, wc = wave & 1;
    f32x4 acc[4][4];
    #pragma unroll
    for (int m = 0; m < 4; ++m)
        #pragma unroll
        for (int n = 0; n < 4; ++n) acc[m][n] = (f32x4){0.f, 0.f, 0.f, 0.f};

    for (int k0 = 0; k0 < F_DIMC; k0 += GEMM_BK) {
        #pragma unroll
        for (int s = 0; s < 4; ++s) {
            int e = s * 2048 + tid * 8;
            int row = e >> 6, col = e & 63;
            __builtin_amdgcn_global_load_lds(
                (const __attribute__((address_space(1))) void*)(A + (size_t)(m0 + row) * F_DIMC + (k0 + col)),
                (__attribute__((address_space(3))) void*)(&As[e]), 16, 0, 0);
        }
        #pragma unroll
        for (int s = 0; s < 4; ++s) {
            int e = s * 2048 + tid * 8;
            int row = e >> 6, col = e & 63;
            __builtin_amdgcn_global_load_lds(
                (const __attribute__((address_space(1))) void*)(Bw + (size_t)(n0 + row) * F_DIMC + (k0 + col)),
                (__attribute__((address_space(3))) void*)(&Bs[e]), 16, 0, 0);
        }
        __syncthreads();
        #pragma unroll
        for (int kk = 0; kk < GEMM_BK; kk += 32) {
            const int lr = lane & 15;
            const int lk = kk + (lane >> 4) * 8;
            bf16x8 af[4], bfr[4];
            #pragma unroll
            for (int m = 0; m < 4; ++m)
                af[m] = *(const bf16x8*)&As[(wr * 64 + m * 16 + lr) * GEMM_BK + lk];
            #pragma unroll
            for (int n = 0; n < 4; ++n)
                bfr[n] = *(const bf16x8*)&Bs[(wc * 64 + n * 16 + lr) * GEMM_BK + lk];
            #pragma unroll
            for (int m = 0; m < 4; ++m)
                #pragma unroll
                for (int n = 0; n < 4; ++n)
                    acc[m][n] = __builtin_amdgcn_mfma_f32_16x16x32_bf16(af[m], bfr[n], acc[m][n], 0, 0, 0);
        }
        __syncthreads();
    }
    const int lr0 = (lane >> 4) * 4;
    const int lc = lane & 15;
    #pragma unroll
    for (int m = 0; m < 4; ++m)
        #pragma unroll
        for (int n = 0; n < 4; ++n)
            #pragma unroll
            for (int j = 0; j < 4; ++j) {
                int row = m0 + wr * 64 + m * 16 + lr0 + j;
                int col = n0 + wc * 64 + n * 16 + lc;
                float v = acc[m][n][j];
                if (z == 2) v = 1.f / (1.f + __expf(-v));
                C[(size_t)row * F_DIMC + col] = v;
            }
}

// generic GEMM with fused epilogues
// EPI: 1 = sigmoid->f32, 2 = relu^2 -> bf16, 3 = Cf += out,
//      4 = Cf += aux*out, 5 = Cf += out + bias[col]
template<int EPI>
__global__ __launch_bounds__(256)
void gemm_bt(const bf16* __restrict__ A, const bf16* __restrict__ Bw,
             int K, int Nout,
             float* __restrict__ Cf, bf16* __restrict__ Cb,
             const float* __restrict__ aux, const float* __restrict__ bias)
{
    __shared__ __align__(16) bf16 As[128 * GEMM_BK];
    __shared__ __align__(16) bf16 Bs[128 * GEMM_BK];
    const int tid = threadIdx.x;
    const int m0 = blockIdx.x * 128;
    const int n0 = blockIdx.y * 128;
    const int lane = tid & 63;
    const int wave = tid >> 6;
    const int wr = wave >> 1, wc = wave & 1;
    f32x4 acc[4][4];
    #pragma unroll
    for (int m = 0; m < 4; ++m)
        #pragma unroll
        for (int n = 0; n < 4; ++n) acc[m][n] = (f32x4){0.f, 0.f, 0.f, 0.f};

    for (int k0 = 0; k0 < K; k0 += GEMM_BK) {
        #pragma unroll
        for (int s = 0; s < 4; ++s) {
            int e = s * 2048 + tid * 8;
            int row = e >> 6, col = e & 63;
            __builtin_amdgcn_global_load_lds(
                (const __attribute__((address_space(1))) void*)(A + (size_t)(m0 + row) * K + (k0 + col)),
                (__attribute__((address_space(3))) void*)(&As[e]), 16, 0, 0);
        }
        #pragma unroll
        for (int s = 0; s < 4; ++s) {
            int e = s * 2048 + tid * 8;
            int row = e >> 6, col = e & 63;
            __builtin_amdgcn_global_load_lds(
                (const __attribute__((address_space(1))) void*)(Bw + (size_t)(n0 + row) * K + (k0 + col)),
                (__attribute__((address_space(3))) void*)(&Bs[e]), 16, 0, 0);
        }
        __syncthreads();
        #pragma unroll
        for (int kk = 0; kk < GEMM_BK; kk += 32) {
            const int lr = lane & 15;
            const int lk = kk + (lane >> 4) * 8;
            bf16x8 af[4], bfr[4];
            #pragma unroll
            for (int m = 0; m < 4; ++m)
                af[m] = *(const bf16x8*)&As[(wr * 64 + m * 16 + lr) * GEMM_BK + lk];
            #pragma unroll
            for (int n = 0; n < 4; ++n)
                bfr[n] = *(const bf16x8*)&Bs[(wc * 64 + n * 16 + lr) * GEMM_BK + lk];
            #pragma unroll
            for (int m = 0; m < 4; ++m)
                #pragma unroll
                for (int n = 0; n < 4; ++n)
                    acc[m][n] = __builtin_amdgcn_mfma_f32_16x16x32_bf16(af[m], bfr[n], acc[m][n], 0, 0, 0);
        }
        __syncthreads();
    }
    const int lr0 = (lane >> 4) * 4;
    const int lc = lane & 15;
    #pragma unroll
    for (int m = 0; m < 4; ++m) {
        #pragma unroll
        for (int n = 0; n < 4; ++n) {
            #pragma unroll
            for (int j = 0; j < 4; ++j) {
                int row = m0 + wr * 64 + m * 16 + lr0 + j;
                int col = n0 + wc * 64 + n * 16 + lc;
                size_t cidx = (size_t)row * Nout + col;
                float v = acc[m][n][j];
                if constexpr (EPI == 1) Cf[cidx] = 1.f / (1.f + __expf(-v));
                else if constexpr (EPI == 2) { float t = fmaxf(v, 0.f); Cb[cidx] = __float2bfloat16(t * t); }
                else if constexpr (EPI == 3) Cf[cidx] += v;
                else if constexpr (EPI == 4) Cf[cidx] += aux[cidx] * v;
                else if constexpr (EPI == 5) Cf[cidx] += v + bias[col];
            }
        }
    }
}

// ---------------- final (N,F) -> (F,H,W) transpose ---------------------------
__global__ __launch_bounds__(256)
void transpose_out_k(const float* __restrict__ d, float* __restrict__ out)
{
    __shared__ float tile[32][33];
    const int n0 = blockIdx.x * 32, f0 = blockIdx.y * 32;
    const int tx = threadIdx.x, ty = threadIdx.y;
    for (int r = ty; r < 32; r += 8) tile[r][tx] = d[(size_t)(n0 + r) * F_DIMC + f0 + tx];
    __syncthreads();
    for (int r = ty; r < 32; r += 8) out[(size_t)(f0 + r) * NTOK + n0 + tx] = tile[tx][r];
}

// =============================================================================
extern "C" void kernel_launch(void* const* d_in, const int* in_sizes, int n_in,
                              void* d_out, int out_size, void* d_ws, size_t ws_size,
                              hipStream_t stream)
{
    if (n_in < 30) return;
    const float* x        = (const float*)d_in[0];
    const float* cin_w1   = (const float*)d_in[1];
    const float* cin_b1   = (const float*)d_in[2];
    const float* cin_w2   = (const float*)d_in[3];
    const float* cin_b2   = (const float*)d_in[4];
    const float* ln0_w    = (const float*)d_in[5];
    const float* ln0_b    = (const float*)d_in[6];
    const float* ln1_w    = (const float*)d_in[7];
    const float* ln1_b    = (const float*)d_in[8];
    const float* ln2_w    = (const float*)d_in[9];
    const float* ln2_b    = (const float*)d_in[10];
    const float* att_tmk  = (const float*)d_in[11];
    const float* att_tmv  = (const float*)d_in[12];
    const float* att_tmr  = (const float*)d_in[13];
    const float* ffn_tmk  = (const float*)d_in[14];
    const float* ffn_tmr  = (const float*)d_in[15];
    const float* att_tf   = (const float*)d_in[16];
    /* d_in[17] = att_td, unused by the reference's single step */
    const float* att_kw   = (const float*)d_in[18];
    const float* att_vw   = (const float*)d_in[19];
    const float* att_rw   = (const float*)d_in[20];
    const float* att_ow   = (const float*)d_in[21];
    const float* ffn_rw   = (const float*)d_in[22];
    const float* ffn_kw   = (const float*)d_in[23];
    const float* ffn_vw   = (const float*)d_in[24];
    const float* spa_dw_w = (const float*)d_in[25];
    const float* spa_dw_b = (const float*)d_in[26];
    const float* spa_pw_w = (const float*)d_in[27];
    const float* spa_pw_b = (const float*)d_in[28];
    const float* state0   = (const float*)d_in[29];
    float* out = (float*)d_out;

    const size_t NF = (size_t)NTOK * F_DIMC;
    char* wsp = (char*)d_ws;
    size_t off = 0;
    auto alloc = [&](size_t bytes) -> void* {
        void* p = wsp + off;
        off += (bytes + 255) & ~(size_t)255;
        return p;
    };
    float* d_buf = (float*)alloc(NF * 4);
    float* Gk    = (float*)alloc(NF * 4);
    float* Gv    = (float*)alloc(NF * 4);
    float* Gr    = (float*)alloc(NF * 4);
    bf16*  xk    = (bf16*)alloc(NF * 2);
    bf16*  xv    = (bf16*)alloc(NF * 2);
    bf16*  xr    = (bf16*)alloc(NF * 2);
    bf16*  ab    = (bf16*)alloc(NF * 2);              // rwkv / dwconv-out (reused)
    bf16*  kkb   = (bf16*)alloc((size_t)NTOK * FHC * 2);
    const size_t WSQ = (size_t)NLAY * F_DIMC * F_DIMC;
    bf16* kwb  = (bf16*)alloc(WSQ * 2);
    bf16* vwb  = (bf16*)alloc(WSQ * 2);
    bf16* rwb  = (bf16*)alloc(WSQ * 2);
    bf16* owb  = (bf16*)alloc(WSQ * 2);
    bf16* frwb = (bf16*)alloc(WSQ * 2);
    bf16* fkwb = (bf16*)alloc((size_t)NLAY * FHC * F_DIMC * 2);
    bf16* fvwb = (bf16*)alloc((size_t)NLAY * F_DIMC * FHC * 2);
    bf16* pwb  = (bf16*)alloc(WSQ * 2);
    float* dwT = (float*)alloc((size_t)NLAY * 49 * F_DIMC * 4);
    if (off > ws_size) return;   // workspace too small -> clean zero-output failure

    {
        Cvt6 c6;
        c6.s[0] = att_kw;  c6.d[0] = kwb;
        c6.s[1] = att_vw;  c6.d[1] = vwb;
        c6.s[2] = att_rw;  c6.d[2] = rwb;
        c6.s[3] = att_ow;  c6.d[3] = owb;
        c6.s[4] = ffn_rw;  c6.d[4] = frwb;
        c6.s[5] = spa_pw_w; c6.d[5] = pwb;
        cvt6_k<<<dim3(((int)WSQ + 255) / 256, 6), dim3(256), 0, stream>>>(c6, (int)WSQ);
        Cvt2 c2;
        c2.s[0] = ffn_kw; c2.d[0] = fkwb;
        c2.s[1] = ffn_vw; c2.d[1] = fvwb;
        int n2 = NLAY * FHC * F_DIMC;
        cvt2_k<<<dim3((n2 + 255) / 256, 2), dim3(256), 0, stream>>>(c2, n2);
        int n = NLAY * 49 * F_DIMC;
        dw_transpose_k<<<dim3((n + 255) / 256), dim3(256), 0, stream>>>(spa_dw_w, dwT, n);
    }

    stem2_k<<<dim3(IMGH * 10, 4), dim3(256), 0, stream>>>(x, cin_w1, cin_b1, cin_w2, cin_b2, d_buf);

    for (int i = 0; i < NLAY; ++i) {
        const float* sp_ff = state0 + (size_t)(5 * i + 0) * NF;
        const float* sp_at = state0 + (size_t)(5 * i + 1) * NF;
        const float* aa    = state0 + (size_t)(5 * i + 2) * NF;
        const float* bb    = state0 + (size_t)(5 * i + 3) * NF;
        const float* pp    = state0 + (size_t)(5 * i + 4) * NF;
        const float* l1w = ln1_w + i * F_DIMC, *l1b = ln1_b + i * F_DIMC;
        const float* l2w = ln2_w + i * F_DIMC, *l2b = ln2_b + i * F_DIMC;
        const float* tmk = att_tmk + i * F_DIMC, *tmv = att_tmv + i * F_DIMC, *tmr = att_tmr + i * F_DIMC;
        const float* ftmk = ffn_tmk + i * F_DIMC, *ftmr = ffn_tmr + i * F_DIMC;
        const float* tf = att_tf + i * F_DIMC;
        const bf16* kw_i  = kwb  + (size_t)i * F_DIMC * F_DIMC;
        const bf16* vw_i  = vwb  + (size_t)i * F_DIMC * F_DIMC;
        const bf16* rw_i  = rwb  + (size_t)i * F_DIMC * F_DIMC;
        const bf16* ow_i  = owb  + (size_t)i * F_DIMC * F_DIMC;
        const bf16* frw_i = frwb + (size_t)i * F_DIMC * F_DIMC;
        const bf16* fkw_i = fkwb + (size_t)i * FHC * F_DIMC;
        const bf16* fvw_i = fvwb + (size_t)i * F_DIMC * FHC;
        const bf16* pw_i  = pwb  + (size_t)i * F_DIMC * F_DIMC;
        const float* dwT_i = dwT + (size_t)i * 49 * F_DIMC;
        const float* dwb_i = spa_dw_b + i * F_DIMC;
        const float* pwbias_i = spa_pw_b + i * F_DIMC;

        if (i == 0)
            lnmix_sa_k<true><<<dim3(NTOK / 4), dim3(256), 0, stream>>>(
                d_buf, sp_at, ln0_w, ln0_b, l1w, l1b, tmk, tmv, tmr, xk, xv, xr);
        else
            lnmix_sa_k<false><<<dim3(NTOK / 4), dim3(256), 0, stream>>>(
                d_buf, sp_at, ln0_w, ln0_b, l1w, l1b, tmk, tmv, tmr, xk, xv, xr);

        G3 g3;
        g3.A0 = xk; g3.A1 = xv; g3.A2 = xr;
        g3.W0 = kw_i; g3.W1 = vw_i; g3.W2 = rw_i;
        g3.C0 = Gk; g3.C1 = Gv; g3.C2 = Gr;
        gemm3_k<<<dim3(NTOK / 128, 2, 3), dim3(256), 0, stream>>>(g3);

        wkv_k<<<dim3((int)(NF / 4 / 256)), dim3(256), 0, stream>>>(Gr, Gk, Gv, aa, bb, pp, tf, ab);
        gemm_bt<3><<<dim3(NTOK / 128, 2), dim3(256), 0, stream>>>(ab, ow_i, F_DIMC, F_DIMC, d_buf, nullptr, nullptr, nullptr);

        lnmix_ff_k<<<dim3(NTOK / 4), dim3(256), 0, stream>>>(d_buf, sp_ff, l2w, l2b, ftmk, ftmr, xk, xr);
        gemm_bt<1><<<dim3(NTOK / 128, 2), dim3(256), 0, stream>>>(xr, frw_i, F_DIMC, F_DIMC, Gr, nullptr, nullptr, nullptr);
        gemm_bt<2><<<dim3(NTOK / 128, 8), dim3(256), 0, stream>>>(xk, fkw_i, F_DIMC, FHC, nullptr, kkb, nullptr, nullptr);
        gemm_bt<4><<<dim3(NTOK / 128, 2), dim3(256), 0, stream>>>(kkb, fvw_i, FHC, F_DIMC, d_buf, nullptr, Gr, nullptr);

        dwconv_k<<<dim3(IMGW / 4, IMGH / 4, 4), dim3(64, 4), 0, stream>>>(d_buf, dwT_i, dwb_i, ab);
        gemm_bt<5><<<dim3(NTOK / 128, 2), dim3(256), 0, stream>>>(ab, pw_i, F_DIMC, F_DIMC, d_buf, nullptr, nullptr, pwbias_i);
    }

    transpose_out_k<<<dim3(NTOK / 32, F_DIMC / 32), dim3(32, 8), 0, stream>>>(d_buf, out);
}